// Round 3
// baseline (15081.287 us; speedup 1.0000x reference)
//
#include <hip/hip_runtime.h>
#include <stdint.h>

// Problem constants
#define BB 512
#define TT 82
#define DD 129
#define DXP 256      // x K padded to multiple of 128
#define HH 1024
#define G4 4096
#define NOUT 128
#define NSTEPS 100

typedef unsigned short u16;
typedef __attribute__((ext_vector_type(8))) __bf16 bf16x8;
typedef __attribute__((ext_vector_type(8))) short short8;
typedef __attribute__((ext_vector_type(16))) float f32x16;

__device__ __forceinline__ u16 f2bf(float f) {
  uint32_t u = __builtin_bit_cast(uint32_t, f);
  u += 0x7fffu + ((u >> 16) & 1u);   // round to nearest even
  return (u16)(u >> 16);
}
__device__ __forceinline__ float sigm(float x) { return 1.f / (1.f + __expf(-x)); }
__device__ __forceinline__ float tanhfast(float x) {
  float ax = fabsf(x);
  float e = __expf(2.f * ax);
  float t = 1.f - 2.f / (e + 1.f);
  return copysignf(t, x);
}
__device__ __forceinline__ void glds16(const void* g, void* l) {
  __builtin_amdgcn_global_load_lds((const __attribute__((address_space(1))) void*)g,
                                   (__attribute__((address_space(3))) void*)l, 16, 0, 0);
}

// Fused step GEMM: G[M,N] = A0[M,K0] @ W[:, :K0]^T + A1[M,K1] @ W[:, K0:]^T + bias
//   W is the combined [N, K0+K1] bf16 matrix (rows gate-permuted when FUSE=1:
//   perm row n <- orig row (n&3)*1024 + (n>>2), i.e. gate = n&3, unit = n>>2).
// Tile: BM=64 (blockIdx.y), BN=128 (blockIdx.x); 256 thr = 4 waves partitioning N
// (wave tile 64x32), MFMA 32x32x16_bf16 (2 m-tiles per wave).
// A via LDS (BK=128 chunks, XOR-swizzled, double-buffered, 4x cross-wave reuse).
// B direct global->VGPR (fetched once per block either way), register double-buffer.
// FUSE=1: epilogue gathers the 4 gates of each unit via ds_bpermute and applies the
//   LSTM cell: c fp32 in-place, h bf16 -> hnext (mask: t>=0 encoder, frozen rows
//   copy h from A0 = h_prev). FUSE=0 (fc): fout fp32 strided + foutb bf16 (stride 256).
template <int K0, int K1, int FUSE>
__global__ __launch_bounds__(256) void step_gemm(
    const u16* __restrict__ A0, const u16* __restrict__ A1,
    const u16* __restrict__ W, const float* __restrict__ bias,
    float* __restrict__ cst, u16* __restrict__ hnext,
    const int* __restrict__ lengths, int t,
    float* __restrict__ fout, u16* __restrict__ foutb)
{
  constexpr int KT = K0 + K1;
  constexpr int NCH = KT >> 7;     // BK=128 chunks (always even here)
  constexpr int NCH0 = K0 >> 7;
  __shared__ __align__(16) u16 Abuf[2][64 * 128];   // 16 KB x2
  const int tid = threadIdx.x;
  const int lane = tid & 63;
  const int w = tid >> 6;
  const int l31 = lane & 31;
  const int hi = lane >> 5;
  const int m0 = blockIdx.y * 64;
  const int n0 = blockIdx.x * 128;
  const int nw = n0 + w * 32;

  // A chunk c -> LDS buf. Slot S (16B) holds row r=S>>4, chunk q=(S&15)^(r&7).
  auto stage = [&](int c, int buf) {
    #pragma unroll
    for (int j = 0; j < 4; ++j) {
      int S = j * 256 + tid;
      int r = S >> 4;
      int q = (S & 15) ^ (r & 7);
      const u16* src;
      if (c < NCH0) src = A0 + (size_t)(m0 + r) * K0 + c * 128 + q * 8;
      else          src = A1 + (size_t)(m0 + r) * K1 + (c - NCH0) * 128 + q * 8;
      glds16(src, &Abuf[buf][(size_t)(j * 256 + w * 64) * 8]);
    }
  };

  const u16* Bbase = W + (size_t)(nw + l31) * KT + hi * 8;
  auto loadB = [&](bf16x8 (&dst)[8], int c) {
    #pragma unroll
    for (int kk = 0; kk < 8; ++kk)
      dst[kk] = __builtin_bit_cast(bf16x8, *(const short8*)(Bbase + c * 128 + kk * 16));
  };

  f32x16 acc0 = {}, acc1 = {};
  const int ra = l31;        // A-frag rows (m-tile 0)
  const int rb = 32 + l31;   // A-frag rows (m-tile 1)
  const int rsw = l31 & 7;   // same for ra and rb
  auto compute = [&](const u16* Ab, bf16x8 (&B)[8]) {
    #pragma unroll
    for (int kk = 0; kk < 8; ++kk) {
      int qk = kk * 2 + hi;
      int qs = qk ^ rsw;
      bf16x8 a0 = __builtin_bit_cast(bf16x8, *(const short8*)&Ab[(size_t)(ra * 16 + qs) * 8]);
      bf16x8 a1 = __builtin_bit_cast(bf16x8, *(const short8*)&Ab[(size_t)(rb * 16 + qs) * 8]);
      acc0 = __builtin_amdgcn_mfma_f32_32x32x16_bf16(a0, B[kk], acc0, 0, 0, 0);
      acc1 = __builtin_amdgcn_mfma_f32_32x32x16_bf16(a1, B[kk], acc1, 0, 0, 0);
    }
  };

  bf16x8 Bb0[8], Bb1[8];
  stage(0, 0);
  loadB(Bb0, 0);
  #pragma unroll 1
  for (int c = 0; c < NCH; c += 2) {
    __syncthreads();                               // A chunk c ready
    stage(c + 1, 1);
    loadB(Bb1, c + 1);
    compute(Abuf[0], Bb0);
    __syncthreads();                               // A chunk c+1 ready
    if (c + 2 < NCH) { stage(c + 2, 0); loadB(Bb0, c + 2); }
    compute(Abuf[1], Bb1);
  }

  // Epilogue. C/D mapping (32x32): col = lane&31, row = (r&3)+8*(r>>2)+4*(lane>>5).
  const float bv = bias[nw + l31];
  if constexpr (FUSE) {
    const int t0 = lane & 3;          // my gate index
    const int sbase = lane & ~3;
    const int u = (nw + l31) >> 2;    // unit
    #pragma unroll
    for (int mt = 0; mt < 2; ++mt) {
      #pragma unroll
      for (int r = 0; r < 16; ++r) {
        float v = (mt ? acc1[r] : acc0[r]) + bv;
        float gI = __shfl(v, sbase);
        float gF = __shfl(v, sbase | 1);
        float gG = __shfl(v, sbase | 2);
        float gO = __shfl(v, sbase | 3);
        int m = m0 + mt * 32 + (r & 3) + 8 * (r >> 2) + 4 * hi;
        size_t idx = ((size_t)m << 10) + u;
        bool upd = (t < 0) || (t < lengths[m]);
        if (t0 == 0) {
          if (upd) {
            float cv = cst[idx];
            float cn = sigm(gF) * cv + sigm(gI) * tanhfast(gG);
            float hn = sigm(gO) * tanhfast(cn);
            cst[idx] = cn;
            hnext[idx] = f2bf(hn);
          } else {
            hnext[idx] = A0[idx];   // carry h through (c untouched)
          }
        }
      }
    }
  } else {
    #pragma unroll
    for (int mt = 0; mt < 2; ++mt) {
      #pragma unroll
      for (int r = 0; r < 16; ++r) {
        int m = m0 + mt * 32 + (r & 3) + 8 * (r >> 2) + 4 * hi;
        int n = nw + l31;
        float v = (mt ? acc1[r] : acc0[r]) + bv;
        fout[(size_t)m * (NSTEPS * NOUT) + n] = v;
        foutb[m * 256 + n] = f2bf(v);
      }
    }
  }
}

// Combined weight build: dst[n][k] (KT=1024+K1 wide, bf16):
//   k<1024 -> Whh[orig][k]; else -> Wih[orig][k-1024] (zero-padded past Cih).
// perm: orig = (n&3)*1024 + (n>>2).
__global__ void conv_wcomb(const float* __restrict__ hh, const float* __restrict__ ih,
                           int Cih, int K1, int perm, u16* __restrict__ dst, int total)
{
  int idx = blockIdx.x * 256 + threadIdx.x;
  if (idx >= total) return;
  const int KT = 1024 + K1;
  int k = idx % KT;
  int n = idx / KT;
  int orig = perm ? ((n & 3) * 1024 + (n >> 2)) : n;
  float v;
  if (k < 1024) v = hh[(size_t)orig * 1024 + k];
  else { int kk = k - 1024; v = (kk < Cih) ? ih[(size_t)orig * Cih + kk] : 0.f; }
  dst[idx] = f2bf(v);
}

__global__ void conv_bias(const float* __restrict__ b1, const float* __restrict__ b2,
                          float* __restrict__ dst, int n_count, int perm)
{
  int n = blockIdx.x * 256 + threadIdx.x;
  if (n >= n_count) return;
  int orig = perm ? ((n & 3) * 1024 + (n >> 2)) : n;
  dst[n] = b1[orig] + (b2 ? b2[orig] : 0.f);
}

// x [B,T,129] fp32 -> xb [T,B,256] bf16 zero-padded
__global__ void conv_x(const float* __restrict__ x, u16* __restrict__ xb)
{
  int idx = blockIdx.x * 256 + threadIdx.x;
  if (idx >= TT * BB * DXP) return;
  int k = idx & (DXP - 1);
  int tb = idx / DXP;
  int b = tb & (BB - 1);
  int t = tb / BB;
  xb[idx] = f2bf(k < DD ? x[((size_t)b * TT + t) * DD + k] : 0.f);
}

extern "C" void kernel_launch(void* const* d_in, const int* in_sizes, int n_in,
                              void* d_out, int out_size, void* d_ws, size_t ws_size,
                              hipStream_t stream) {
  (void)in_sizes; (void)n_in; (void)out_size; (void)ws_size;
  const float* x     = (const float*)d_in[0];
  const int*   lens  = (const int*)d_in[1];
  const float* eWih0 = (const float*)d_in[2];
  const float* eWhh0 = (const float*)d_in[3];
  const float* ebih0 = (const float*)d_in[4];
  const float* ebhh0 = (const float*)d_in[5];
  const float* eWih1 = (const float*)d_in[6];
  const float* eWhh1 = (const float*)d_in[7];
  const float* ebih1 = (const float*)d_in[8];
  const float* ebhh1 = (const float*)d_in[9];
  const float* dWih0 = (const float*)d_in[10];
  const float* dWhh0 = (const float*)d_in[11];
  const float* dbih0 = (const float*)d_in[12];
  const float* dbhh0 = (const float*)d_in[13];
  const float* dWih1 = (const float*)d_in[14];
  const float* dWhh1 = (const float*)d_in[15];
  const float* dbih1 = (const float*)d_in[16];
  const float* dbhh1 = (const float*)d_in[17];
  const float* fcW   = (const float*)d_in[18];
  const float* fcb   = (const float*)d_in[19];
  float* out = (float*)d_out;

  char* p = (char*)d_ws;
  auto carve = [&](size_t bytes) -> void* {
    void* q = (void*)p;
    p += (bytes + 255) & ~(size_t)255;
    return q;
  };
  u16* Wc_e0 = (u16*)carve((size_t)G4 * 1280 * 2);
  u16* Wc_e1 = (u16*)carve((size_t)G4 * 2048 * 2);
  u16* Wc_d0 = (u16*)carve((size_t)G4 * 1280 * 2);
  u16* Wc_d1 = (u16*)carve((size_t)G4 * 2048 * 2);
  u16* fcWb  = (u16*)carve((size_t)NOUT * HH * 2);
  float* be0 = (float*)carve((size_t)G4 * 4);
  float* be1 = (float*)carve((size_t)G4 * 4);
  float* bd0 = (float*)carve((size_t)G4 * 4);
  float* bd1 = (float*)carve((size_t)G4 * 4);
  float* bfc = (float*)carve((size_t)NOUT * 4);
  u16* xb    = (u16*)carve((size_t)TT * BB * DXP * 2);
  u16* h0p[2] = { (u16*)carve((size_t)BB * HH * 2), (u16*)carve((size_t)BB * HH * 2) };
  u16* h1p[2] = { (u16*)carve((size_t)BB * HH * 2), (u16*)carve((size_t)BB * HH * 2) };
  u16* outb  = (u16*)carve((size_t)BB * 256 * 2);
  float* c0  = (float*)carve((size_t)BB * HH * 4);
  float* c1  = (float*)carve((size_t)BB * HH * 4);

  auto wc = [&](const float* hh, const float* ih, int Cih, int K1, int perm, u16* dst, int R) {
    int total = R * (1024 + K1);
    conv_wcomb<<<dim3((total + 255) / 256), dim3(256), 0, stream>>>(hh, ih, Cih, K1, perm, dst, total);
  };
  wc(eWhh0, eWih0, DD,   256,  1, Wc_e0, G4);
  wc(eWhh1, eWih1, HH,   1024, 1, Wc_e1, G4);
  wc(dWhh0, dWih0, NOUT, 256,  1, Wc_d0, G4);
  wc(dWhh1, dWih1, HH,   1024, 1, Wc_d1, G4);
  wc(fcW,   fcW,   0,    0,    0, fcWb,  NOUT);
  conv_bias<<<dim3(16), dim3(256), 0, stream>>>(ebih0, ebhh0, be0, G4, 1);
  conv_bias<<<dim3(16), dim3(256), 0, stream>>>(ebih1, ebhh1, be1, G4, 1);
  conv_bias<<<dim3(16), dim3(256), 0, stream>>>(dbih0, dbhh0, bd0, G4, 1);
  conv_bias<<<dim3(16), dim3(256), 0, stream>>>(dbih1, dbhh1, bd1, G4, 1);
  conv_bias<<<dim3(1), dim3(256), 0, stream>>>(fcb, (const float*)nullptr, bfc, NOUT, 0);
  conv_x<<<dim3((TT * BB * DXP + 255) / 256), dim3(256), 0, stream>>>(x, xb);

  hipMemsetAsync(h0p[0], 0, (size_t)BB * HH * 2, stream);
  hipMemsetAsync(h1p[0], 0, (size_t)BB * HH * 2, stream);
  hipMemsetAsync(outb, 0, (size_t)BB * 256 * 2, stream);   // dec step 0 input = 0
  hipMemsetAsync(c0, 0, (size_t)BB * HH * 4, stream);
  hipMemsetAsync(c1, 0, (size_t)BB * HH * 4, stream);

  const dim3 gg(G4 / 128, BB / 64);    // (32, 8) = 256 blocks
  const dim3 gfc(1, BB / 64);          // (1, 8)

  // encoder: global step g = t; h_prev = buf[g&1], h_next = buf[(g+1)&1]
  for (int t = 0; t < TT; ++t) {
    const int pr = t & 1, nx = (t + 1) & 1;
    step_gemm<1024, 256, 1><<<gg, 256, 0, stream>>>(
        h0p[pr], xb + (size_t)t * BB * DXP, Wc_e0, be0,
        c0, h0p[nx], lens, t, (float*)nullptr, (u16*)nullptr);
    step_gemm<1024, 1024, 1><<<gg, 256, 0, stream>>>(
        h1p[pr], h0p[nx], Wc_e1, be1,
        c1, h1p[nx], lens, t, (float*)nullptr, (u16*)nullptr);
  }

  // decoder: global step g = TT + s
  for (int s = 0; s < NSTEPS; ++s) {
    const int g = TT + s;
    const int pr = g & 1, nx = (g + 1) & 1;
    step_gemm<1024, 256, 1><<<gg, 256, 0, stream>>>(
        h0p[pr], outb, Wc_d0, bd0,
        c0, h0p[nx], lens, -1, (float*)nullptr, (u16*)nullptr);
    step_gemm<1024, 1024, 1><<<gg, 256, 0, stream>>>(
        h1p[pr], h0p[nx], Wc_d1, bd1,
        c1, h1p[nx], lens, -1, (float*)nullptr, (u16*)nullptr);
    step_gemm<1024, 0, 0><<<gfc, 256, 0, stream>>>(
        h1p[nx], (const u16*)nullptr, fcWb, bfc,
        (float*)nullptr, (u16*)nullptr, (const int*)nullptr, -1,
        out + (size_t)s * NOUT, outb);
  }
}